// Round 1
// 204.937 us; speedup vs baseline: 1.0525x; 1.0525x over previous
//
#include <hip/hip_runtime.h>
#include <hip/hip_fp16.h>

#define N_NODES 80000
#define N_EDGES 1280000
#define IN_CH 128
#define HID 64
#define OUT_CH 32

#define NBUCK 625      // 128 dst-nodes per bucket; 625*128 == 80000
#define CAP 3072       // bucket capacity; Poisson(mean=2048) -> +20 sigma safe
#define BIN_BLOCKS 256

typedef float vf2 __attribute__((ext_vector_type(2)));
typedef float vf4 __attribute__((ext_vector_type(4)));
typedef short short8 __attribute__((ext_vector_type(8)));   // 8 bf16 (4 VGPRs)
typedef float floatx4 __attribute__((ext_vector_type(4)));  // MFMA acc

// ---- bf16 pack (RNE) for MFMA staging ----
__device__ __forceinline__ unsigned bf16rn(float x) {
    unsigned u = __float_as_uint(x);
    return (u + 0x7FFFu + ((u >> 16) & 1u)) >> 16;
}
__device__ __forceinline__ unsigned packbf2(float a, float b) {
    return bf16rn(a) | (bf16rn(b) << 16);
}
// ---- f16 pack/unpack for gather tables ----
__device__ __forceinline__ float hl(unsigned u) {
    return __half2float(__ushort_as_half((unsigned short)(u & 0xFFFFu)));
}
__device__ __forceinline__ float hh(unsigned u) {
    return __half2float(__ushort_as_half((unsigned short)(u >> 16)));
}
__device__ __forceinline__ unsigned pack2h(float a, float b) {
    return (unsigned)__half_as_ushort(__float2half_rn(a)) |
           ((unsigned)__half_as_ushort(__float2half_rn(b)) << 16);
}

// ---------------- fused K1: bin (blocks 0..255) + MFMA GEMM1 (blocks 256..880) ----
// bin: packed word src | dstLocal<<17 into per-bucket arrays.
// GEMM1: h1[n][:] = x[n] @ W1 (UNSCALED), f16 table [N][64] ushort.
// MFMA 16x16x32 bf16: per wave 32 nodes x 64 cols, K=128 in 4 steps.
__global__ __launch_bounds__(256) void k_bin_gemm1(
        const int* __restrict__ src, const int* __restrict__ dst,
        int* __restrict__ gcur, unsigned int* __restrict__ binned,
        const float* __restrict__ x, const float* __restrict__ W1,
        unsigned short* __restrict__ h1h) {
    __shared__ unsigned short smem_u[26112];  // 52224 B
    int bid = blockIdx.x, t = threadIdx.x;
    if (bid < BIN_BLOCKS) {
        // ---- bin path ----
        int* hist = (int*)smem_u;
        int* lcur = hist + NBUCK;
        const int chunk = N_EDGES / BIN_BLOCKS;  // 5000
        int e0 = bid * chunk;
        int e1 = e0 + chunk;
        for (int i = t; i < NBUCK; i += 256) hist[i] = 0;
        __syncthreads();
        for (int e = e0 + t; e < e1; e += 256)
            atomicAdd(&hist[dst[e] >> 7], 1);
        __syncthreads();
        for (int i = t; i < NBUCK; i += 256) {
            int h = hist[i];
            lcur[i] = h ? atomicAdd(&gcur[i], h) : 0;
        }
        __syncthreads();
        for (int e = e0 + t; e < e1; e += 256) {
            int d = dst[e];
            int bk = d >> 7;
            int pos = atomicAdd(&lcur[bk], 1);
            if (pos < CAP)
                binned[(size_t)bk * CAP + pos] =
                    (unsigned int)src[e] | ((unsigned int)(d & 127) << 17);
        }
    } else {
        // ---- MFMA GEMM1: sX [128 nodes][136] bf16, sWT [64 cols][136] bf16 ----
        unsigned short* sX = smem_u;              // 128*136
        unsigned short* sWT = smem_u + 128 * 136; // 64*136
        long long nb = (long long)(bid - BIN_BLOCKS) * 128;
        // stage x -> bf16 (row-major, k contiguous)
        for (int it = 0; it < 16; ++it) {
            int idx = t + it * 256;               // 4096 float4 loads
            int node = idx >> 5, k4 = (idx & 31) * 4;
            float4 v = *(const float4*)&x[(nb + node) * IN_CH + k4];
            unsigned u0 = packbf2(v.x, v.y), u1 = packbf2(v.z, v.w);
            *(uint2*)&sX[node * 136 + k4] = (uint2){u0, u1};
        }
        // stage W1^T -> bf16 ([col][k])
        for (int it = 0; it < 8; ++it) {
            int idx = t + it * 256;               // 2048 float4 loads
            int k = idx >> 4, c4 = (idx & 15) * 4;
            float4 w = *(const float4*)&W1[k * 64 + c4];
            sWT[(c4 + 0) * 136 + k] = (unsigned short)bf16rn(w.x);
            sWT[(c4 + 1) * 136 + k] = (unsigned short)bf16rn(w.y);
            sWT[(c4 + 2) * 136 + k] = (unsigned short)bf16rn(w.z);
            sWT[(c4 + 3) * 136 + k] = (unsigned short)bf16rn(w.w);
        }
        __syncthreads();
        int wv = t >> 6, lane = t & 63;
        int lm = lane & 15, q = lane >> 4;
        int m0 = wv * 32;
        floatx4 acc[2][4];
#pragma unroll
        for (int i = 0; i < 2; ++i)
#pragma unroll
            for (int j = 0; j < 4; ++j) acc[i][j] = (floatx4){0.f, 0.f, 0.f, 0.f};
#pragma unroll
        for (int kk = 0; kk < 128; kk += 32) {
            short8 a0 = *(short8*)&sX[(m0 + lm) * 136 + kk + q * 8];
            short8 a1 = *(short8*)&sX[(m0 + 16 + lm) * 136 + kk + q * 8];
#pragma unroll
            for (int ct = 0; ct < 4; ++ct) {
                short8 bfr = *(short8*)&sWT[(ct * 16 + lm) * 136 + kk + q * 8];
                acc[0][ct] = __builtin_amdgcn_mfma_f32_16x16x32_bf16(a0, bfr, acc[0][ct], 0, 0, 0);
                acc[1][ct] = __builtin_amdgcn_mfma_f32_16x16x32_bf16(a1, bfr, acc[1][ct], 0, 0, 0);
            }
        }
        // D layout: col = lane&15, row = q*4 + reg
#pragma unroll
        for (int mt = 0; mt < 2; ++mt)
#pragma unroll
            for (int ct = 0; ct < 4; ++ct)
#pragma unroll
                for (int r = 0; r < 4; ++r) {
                    long long node = nb + m0 + mt * 16 + q * 4 + r;
                    int c = ct * 16 + lm;
                    h1h[node * 64 + c] = __half_as_ushort(__float2half_rn(acc[mt][ct][r]));
                }
    }
}

// ---------------- K2: per-bucket counting sort -> CSR + dinv ----------------
__global__ __launch_bounds__(256) void k_csr(const unsigned int* __restrict__ binned,
                                             const int* __restrict__ cnt,
                                             int* __restrict__ csr,
                                             int* __restrict__ rs, int* __restrict__ re,
                                             float* __restrict__ dinv) {
    __shared__ int deg[128];
    __shared__ int scan[128];
    __shared__ int cur[128];
    int bk = blockIdx.x, t = threadIdx.x;
    int n_e = min(cnt[bk], CAP);
    const unsigned int* eb = binned + (size_t)bk * CAP;
    if (t < 128) deg[t] = 0;
    __syncthreads();
    for (int i = t; i < n_e; i += 256) atomicAdd(&deg[eb[i] >> 17], 1);
    __syncthreads();
    if (t < 128) scan[t] = deg[t];
    __syncthreads();
    for (int off = 1; off < 128; off <<= 1) {
        int v = (t < 128 && t >= off) ? scan[t - off] : 0;
        __syncthreads();
        if (t < 128) scan[t] += v;
        __syncthreads();
    }
    if (t < 128) {
        int incl = scan[t];
        int s = incl - deg[t];
        cur[t] = s;
        int n = bk * 128 + t;
        int base = bk * CAP;
        rs[n] = base + s;
        re[n] = base + incl;
        dinv[n] = rsqrtf((float)(deg[t] + 1));  // +1 self loop
    }
    __syncthreads();
    for (int i = t; i < n_e; i += 256) {
        unsigned int p = eb[i];
        int dL = p >> 17;
        int pos = atomicAdd(&cur[dL], 1);
        csr[bk * CAP + pos] = (int)(p & 0x1FFFF);
    }
}

// ---------------- agg layer 1 + fused GEMM2 ----------------
// Per wave: 2 nodes. 4 quarter-wave streams (16 lanes x uint2 = 128 B/edge),
// unroll 4 -> 16 gathers in flight per wave (2x previous).
// h2[n][f] = relu(dinv[n]*(dinv[n]*h1[n][f] + sum_s dinv[s]*h1[s][f]) + b1[f])
// fused: g2[n][:] = h2[n] @ W2, written as f16-packed table (no h2/GEMM2 pass).
__global__ __launch_bounds__(256) void k_agg64(
        const unsigned int* __restrict__ h1u, const int* __restrict__ csr,
        const int* __restrict__ rs_, const int* __restrict__ re_,
        const float* __restrict__ dinv, const float* __restrict__ b1,
        const float* __restrict__ W2, unsigned int* __restrict__ g2u) {
    __shared__ float sW2[64 * 32];     // 8 KB
    __shared__ float sB1[64];
    __shared__ float sH2[4][2][64];    // per-wave, per-node h2 row
    int t = threadIdx.x;
    // stage W2 + b1 (used only after the post-loop barrier)
    for (int i = t * 2; i < 64 * 32; i += 512)
        *(vf2*)&sW2[i] = *(const vf2*)&W2[i];
    if (t < 32) *(vf2*)&sB1[t * 2] = *(const vf2*)&b1[t * 2];

    int wv = t >> 6, lane = t & 63;
    int nd = lane >> 5;          // which of the wave's 2 nodes
    int q  = (lane >> 4) & 1;    // edge stream within node
    int fo = lane & 15;          // uint2 index -> feats 4fo..4fo+3
    long long n = (long long)blockIdx.x * 8 + wv * 2 + nd;
    int a = rs_[n], b = re_[n];
    float ax = 0.f, ay = 0.f, az = 0.f, aw = 0.f;
    int e = a + q;
    for (; e + 6 < b; e += 8) {
        int s0 = csr[e], s1 = csr[e + 2], s2 = csr[e + 4], s3 = csr[e + 6];
        uint2 u0 = *(const uint2*)&h1u[(size_t)s0 * 32 + 2 * fo]; float d0 = dinv[s0];
        uint2 u1 = *(const uint2*)&h1u[(size_t)s1 * 32 + 2 * fo]; float d1 = dinv[s1];
        uint2 u2 = *(const uint2*)&h1u[(size_t)s2 * 32 + 2 * fo]; float d2 = dinv[s2];
        uint2 u3 = *(const uint2*)&h1u[(size_t)s3 * 32 + 2 * fo]; float d3 = dinv[s3];
        ax += d0 * hl(u0.x); ay += d0 * hh(u0.x); az += d0 * hl(u0.y); aw += d0 * hh(u0.y);
        ax += d1 * hl(u1.x); ay += d1 * hh(u1.x); az += d1 * hl(u1.y); aw += d1 * hh(u1.y);
        ax += d2 * hl(u2.x); ay += d2 * hh(u2.x); az += d2 * hl(u2.y); aw += d2 * hh(u2.y);
        ax += d3 * hl(u3.x); ay += d3 * hh(u3.x); az += d3 * hl(u3.y); aw += d3 * hh(u3.y);
    }
    for (; e < b; e += 2) {
        int s = csr[e];
        uint2 u = *(const uint2*)&h1u[(size_t)s * 32 + 2 * fo];
        float d = dinv[s];
        ax += d * hl(u.x); ay += d * hh(u.x); az += d * hl(u.y); aw += d * hh(u.y);
    }
    // combine the node's two streams: lanes 0..15 (nd=0) / 32..47 (nd=1)
    ax += __shfl_down(ax, 16); ay += __shfl_down(ay, 16);
    az += __shfl_down(az, 16); aw += __shfl_down(aw, 16);
    __syncthreads();   // sW2/sB1 staged; uniform for all threads
    if (q == 0) {
        float dn = dinv[n];
        uint2 un = *(const uint2*)&h1u[(size_t)n * 32 + 2 * fo];
        ax += dn * hl(un.x); ay += dn * hh(un.x);   // self loop
        az += dn * hl(un.y); aw += dn * hh(un.y);
        float4 bb = *(const float4*)&sB1[4 * fo];
        vf4 h2v = {fmaxf(dn * ax + bb.x, 0.f), fmaxf(dn * ay + bb.y, 0.f),
                   fmaxf(dn * az + bb.z, 0.f), fmaxf(dn * aw + bb.w, 0.f)};
        *(vf4*)&sH2[wv][nd][4 * fo] = h2v;
    }
    __syncthreads();
    // fused GEMM2: each lane computes one (node, col) of g2 = h2 @ W2
    int col = lane & 31;
    int nd2 = lane >> 5;
    const float* hrow = sH2[wv][nd2];
    float g = 0.f;
#pragma unroll
    for (int k = 0; k < 64; ++k) g += hrow[k] * sW2[k * 32 + col];
    float g1 = __shfl_down(g, 1);
    float g2v = __shfl_down(g, 2);
    float g3 = __shfl_down(g, 3);
    if ((lane & 3) == 0) {
        long long nn = (long long)blockIdx.x * 8 + wv * 2 + nd2;
        uint2 p = {pack2h(g, g1), pack2h(g2v, g3)};
        *(uint2*)&g2u[(size_t)nn * 16 + (col >> 1)] = p;
    }
}

// ---------------- agg layer 2: F=32, f16 table ----------------
// Eighth-wave (8 lanes x uint2 = 64 B) per edge -> 8 edges in flight, unroll 2.
__global__ __launch_bounds__(256) void k_agg32(
        const unsigned int* __restrict__ g2u, const int* __restrict__ csr,
        const int* __restrict__ rs_, const int* __restrict__ re_,
        const float* __restrict__ dinv, const float* __restrict__ b2,
        float* __restrict__ outp) {
    int n = blockIdx.x * 4 + (threadIdx.x >> 6);
    int lane = threadIdx.x & 63;
    int oc = lane >> 3, fo = lane & 7;  // feats 4fo..4fo+3
    int a = rs_[n], b = re_[n];
    float ax = 0.f, ay = 0.f, az = 0.f, aw = 0.f;
    int e = a + oc;
    for (; e + 8 < b; e += 16) {
        int s0 = csr[e], s1 = csr[e + 8];
        uint2 u0 = *(const uint2*)&g2u[(size_t)s0 * 16 + 2 * fo]; float d0 = dinv[s0];
        uint2 u1 = *(const uint2*)&g2u[(size_t)s1 * 16 + 2 * fo]; float d1 = dinv[s1];
        ax += d0 * hl(u0.x); ay += d0 * hh(u0.x);
        az += d0 * hl(u0.y); aw += d0 * hh(u0.y);
        ax += d1 * hl(u1.x); ay += d1 * hh(u1.x);
        az += d1 * hl(u1.y); aw += d1 * hh(u1.y);
    }
    for (; e < b; e += 8) {
        int s = csr[e];
        uint2 u = *(const uint2*)&g2u[(size_t)s * 16 + 2 * fo];
        float d = dinv[s];
        ax += d * hl(u.x); ay += d * hh(u.x);
        az += d * hl(u.y); aw += d * hh(u.y);
    }
    ax += __shfl_down(ax, 32); ay += __shfl_down(ay, 32);
    az += __shfl_down(az, 32); aw += __shfl_down(aw, 32);
    ax += __shfl_down(ax, 16); ay += __shfl_down(ay, 16);
    az += __shfl_down(az, 16); aw += __shfl_down(aw, 16);
    ax += __shfl_down(ax, 8);  ay += __shfl_down(ay, 8);
    az += __shfl_down(az, 8);  aw += __shfl_down(aw, 8);
    if (oc == 0) {
        float dn = dinv[n];
        uint2 un = *(const uint2*)&g2u[(size_t)n * 16 + 2 * fo];
        ax += dn * hl(un.x); ay += dn * hh(un.x);
        az += dn * hl(un.y); aw += dn * hh(un.y);
        float4 bb = *(const float4*)&b2[4 * fo];
        vf4 o = {dn * ax + bb.x, dn * ay + bb.y, dn * az + bb.z, dn * aw + bb.w};
        __builtin_nontemporal_store(o, (vf4*)&outp[(size_t)n * 32 + 4 * fo]);
    }
}

static inline size_t align256(size_t x) { return (x + 255) & ~(size_t)255; }

extern "C" void kernel_launch(void* const* d_in, const int* in_sizes, int n_in,
                              void* d_out, int out_size, void* d_ws, size_t ws_size,
                              hipStream_t stream) {
    const float* x  = (const float*)d_in[0];
    const int*   ei = (const int*)d_in[1];
    const float* W1 = (const float*)d_in[2];
    const float* b1 = (const float*)d_in[3];
    const float* W2 = (const float*)d_in[4];
    const float* b2 = (const float*)d_in[5];
    float* out = (float*)d_out;

    const int* src = ei;
    const int* dst = ei + N_EDGES;

    // workspace layout (~22 MB)
    char* ws = (char*)d_ws;
    size_t off = 0;
    int* gcur = (int*)(ws + off);              off = align256(off + NBUCK * 4);
    unsigned int* binned = (unsigned int*)(ws + off);
                                               off = align256(off + (size_t)NBUCK * CAP * 4);
    int* csr = (int*)(ws + off);               off = align256(off + (size_t)NBUCK * CAP * 4);
    int* rs  = (int*)(ws + off);               off = align256(off + (size_t)N_NODES * 4);
    int* re  = (int*)(ws + off);               off = align256(off + (size_t)N_NODES * 4);
    float* dinv = (float*)(ws + off);          off = align256(off + (size_t)N_NODES * 4);
    unsigned short* h1h = (unsigned short*)(ws + off);
                                               off = align256(off + (size_t)N_NODES * 64 * 2);
    // g2u must NOT alias h1h: agg64 writes g2 while other blocks still gather h1.
    unsigned int* g2u = (unsigned int*)(ws + off);
                                               off = align256(off + (size_t)N_NODES * 16 * 4);

    (void)hipMemsetAsync(gcur, 0, NBUCK * 4, stream);
    k_bin_gemm1<<<BIN_BLOCKS + N_NODES / 128, 256, 0, stream>>>(src, dst, gcur, binned,
                                                                x, W1, h1h);
    k_csr<<<NBUCK, 256, 0, stream>>>(binned, gcur, csr, rs, re, dinv);
    k_agg64<<<N_NODES / 8, 256, 0, stream>>>((const unsigned int*)h1h, csr, rs, re,
                                             dinv, b1, W2, g2u);
    k_agg32<<<N_NODES / 4, 256, 0, stream>>>(g2u, csr, rs, re, dinv, b2, out);
}